// Round 7
// baseline (69.004 us; speedup 1.0000x reference)
//
#include <hip/hip_runtime.h>
#include <stdint.h>

#define B_N 16
#define C_N 64
#define O_N 64
#define H_N 128
#define W_N 128

typedef short bf16x8 __attribute__((ext_vector_type(8)));
typedef float f32x4 __attribute__((ext_vector_type(4)));
typedef unsigned short u16;
typedef u16 u16x4 __attribute__((ext_vector_type(4)));
typedef u16 u16x8 __attribute__((ext_vector_type(8)));

__device__ __forceinline__ u16 f2bf(float f) {
    uint32_t u = __float_as_uint(f);
    u += 0x7FFFu + ((u >> 16) & 1u);
    return (u16)(u >> 16);
}

// Period-8 swizzle: conflict-free b128 reads on every 8-w window (incl. the
// jsh=+-1 shifted windows). Staging writes pay ~28 cyc/store — accepted
// (LDS pipe not the bottleneck; R4->R5 flatness proved it).
__device__ __forceinline__ int swz(int w) { return (w & 7) << 4; }

// Pre-gather weights into exact B-fragment order.
// v8: thread owns a full j8-row -> ONE coalesced b128 store (was 4 scattered
// u16 stores); reads are 64B-segmented (o consecutive within 16 lanes).
// wf[b][ij][cs][of][l][j8] (bf16); value = weight[b][c*9+ij][o],
// c = cs*32 + (l>>4)*8 + j8,  o = of*16 + (l&15).
__global__ __launch_bounds__(256) void prep_weights(const float* __restrict__ wt,
                                                    u16* __restrict__ wf) {
    int idx = blockIdx.x * 256 + threadIdx.x;   // 16*9*2*4*64 = 73728 threads
    int e = idx;
    int l  = e & 63; e >>= 6;
    int of = e & 3;  e >>= 2;
    int cs = e & 1;  e >>= 1;
    int ij = e % 9;
    int b  = e / 9;
    const int o = of * 16 + (l & 15);
    const int cbase = cs * 32 + (l >> 4) * 8;
    u16x8 pk;
#pragma unroll
    for (int j8 = 0; j8 < 8; ++j8) {
        float v = wt[((size_t)b * 576 + (size_t)(cbase + j8) * 9 + ij) * 64 + o];
        pk[j8] = f2bf(v);
    }
    *reinterpret_cast<u16x8*>(wf + (size_t)idx * 8) = pk;
}

// Main kernel v8: PHASE-STAGGERED blocks. 512 blocks x 256 threads (4 waves),
// 4-row strip each, 64KB LDS -> 2 INDEPENDENT blocks/CU (still 2 waves/SIMD,
// but each SIMD hosts one wave from each block: independent barriers/vmcnt ->
// when block A stalls, block B issues; R6 ledger showed ~85% stall with all
// pipes <50% and 8 lockstep waves). Waves own 64px x 32o (mf=4). Same wreg
// (144 VGPR) + 4-slot circular LDS + restage chassis; per-CU traffic totals
// identical to v7 -> isolates the stagger variable.
__global__ __launch_bounds__(256, 2) void conv_main(const float* __restrict__ x,
                                                    const u16* __restrict__ wf,
                                                    const float* __restrict__ bias,
                                                    float* __restrict__ y) {
    __shared__ u16 xl[4 * 128 * 64];   // 4 slots x [w][c] bf16 = 64 KB, swz

    // XCD-bijective swizzle: 512 wgs, 8 XCDs, chunk 64 -> XCD j owns 2 full b's.
    const int lid = (blockIdx.x & 7) * 64 + (blockIdx.x >> 3);
    const int b   = lid >> 5;
    const int h0  = (lid & 31) * 4;
    const int tid = threadIdx.x;
    const int wid = tid >> 6;
    const int l   = tid & 63;
    const int wave_m = wid >> 1;              // 0..1 -> 64-px band
    const int wave_n = wid & 1;               // 0..1 -> 32-o band
    const int m0 = wave_m * 64;
    const int o0 = wave_n * 32;
    const int lr = l & 15;
    const int lg = l >> 4;

    // staging task: 32 w-quads x 8 cq2 (each covers 2 c-quads)
    const int w4  = tid & 31;
    const int cq2 = tid >> 5;                 // 0..7
    const float* xb = x + (size_t)b * (64 * 128 * 128);
    const u16* wfb  = wf + (size_t)b * 36864;

    auto ldrow = [&](int s, f32x4* d) {
        int hr = (h0 + s + 127) & 127;        // input row h0 + s - 1 (wrap)
#pragma unroll
        for (int half = 0; half < 2; ++half) {
            const float* src = xb + ((size_t)(cq2 * 2 + half) * 4 * 128 + hr) * 128 + w4 * 4;
            d[half * 4 + 0] = *reinterpret_cast<const f32x4*>(src);
            d[half * 4 + 1] = *reinterpret_cast<const f32x4*>(src + 16384);
            d[half * 4 + 2] = *reinterpret_cast<const f32x4*>(src + 32768);
            d[half * 4 + 3] = *reinterpret_cast<const f32x4*>(src + 49152);
        }
    };
    auto wrrow = [&](int slot, const f32x4* d) {
#pragma unroll
        for (int half = 0; half < 2; ++half) {
            const int cq = cq2 * 2 + half;
#pragma unroll
            for (int j = 0; j < 4; ++j) {
                int w = w4 * 4 + j;
                u16x4 pk;
                pk.x = f2bf(d[half * 4 + 0][j]); pk.y = f2bf(d[half * 4 + 1][j]);
                pk.z = f2bf(d[half * 4 + 2][j]); pk.w = f2bf(d[half * 4 + 3][j]);
                int byte = slot * 16384 + w * 128 + cq * 8;
                byte ^= swz(w);
                *reinterpret_cast<u16x4*>(reinterpret_cast<char*>(xl) + byte) = pk;
            }
        }
    };

    // ---- Prologue: x loads first, weights second (vmcnt-ordered) ----
    f32x4 sA[8], sB[8], st[8];
    ldrow(0, sA); ldrow(1, sB);

    bf16x8 wreg[9][2][2];                     // [ij][cs][nf] = 144 VGPRs
#pragma unroll
    for (int ij = 0; ij < 9; ++ij)
#pragma unroll
        for (int cs = 0; cs < 2; ++cs)
#pragma unroll
            for (int nf = 0; nf < 2; ++nf)
                wreg[ij][cs][nf] = *reinterpret_cast<const bf16x8*>(
                    wfb + (size_t)(((ij * 2 + cs) * 4 + wave_n * 2 + nf) * 64 + l) * 8);

    const float bv0 = bias[b * 64 + o0 + lr];
    const float bv1 = bias[b * 64 + o0 + 16 + lr];

    wrrow(0, sA); wrrow(1, sB);
    ldrow(2, sA); wrrow(2, sA);
    ldrow(3, st);                             // s=3 written during row 0
    __syncthreads();

    // ---- 4 output rows. Row r reads s=r..r+2 (slots s&3).
    //      Restage: wrrow s=r+3 -> slot (r+3)&3 at ij2 (data from last row's
    //      ldrow), ldrow s=r+4 at ij5. Barrier after each row (syncs 4 waves).
#pragma unroll
    for (int r = 0; r < 4; ++r) {
        f32x4 acc[4][2];
#pragma unroll
        for (int mf = 0; mf < 4; ++mf)
#pragma unroll
            for (int nf = 0; nf < 2; ++nf)
                acc[mf][nf] = (f32x4){0.f, 0.f, 0.f, 0.f};

#pragma unroll
        for (int ij = 0; ij < 9; ++ij) {
            if (ij == 2 && r < 3) wrrow((r + 3) & 3, st);
            if (ij == 5 && r < 2) ldrow(r + 4, st);

            const int i = ij / 3;
            const int jsh = ij % 3 - 1;
            const int rbase = ((r + i) & 3) * 16384;
#pragma unroll
            for (int cs = 0; cs < 2; ++cs) {
                const int cb = cs * 64 + lg * 16;
                bf16x8 afr[4];
#pragma unroll
                for (int mf = 0; mf < 4; ++mf) {
                    int w = (m0 + mf * 16 + lr + jsh + 128) & 127;
                    int byte = rbase + w * 128 + cb;
                    byte ^= swz(w);
                    afr[mf] = *reinterpret_cast<const bf16x8*>(
                        reinterpret_cast<const char*>(xl) + byte);
                }
#pragma unroll
                for (int mf = 0; mf < 4; ++mf) {
                    acc[mf][0] = __builtin_amdgcn_mfma_f32_16x16x32_bf16(afr[mf], wreg[ij][cs][0], acc[mf][0], 0, 0, 0);
                    acc[mf][1] = __builtin_amdgcn_mfma_f32_16x16x32_bf16(afr[mf], wreg[ij][cs][1], acc[mf][1], 0, 0, 0);
                }
            }
        }

        // ---- Epilogue: D layout col=lane&15 (o), row=(lane>>4)*4+reg (w) ----
        const int h = h0 + r;
#pragma unroll
        for (int nf = 0; nf < 2; ++nf) {
            int o = o0 + nf * 16 + lr;
            float bv = nf ? bv1 : bv0;
#pragma unroll
            for (int mf = 0; mf < 4; ++mf) {
                int w0 = m0 + mf * 16 + lg * 4;
                float* dst = y + (((size_t)b * 64 + o) * 128 + h) * 128 + w0;
                f32x4 out;
                out[0] = acc[mf][nf][0] + bv;
                out[1] = acc[mf][nf][1] + bv;
                out[2] = acc[mf][nf][2] + bv;
                out[3] = acc[mf][nf][3] + bv;
                *reinterpret_cast<f32x4*>(dst) = out;
            }
        }
        if (r < 3) __syncthreads();
    }
}

// Correctness-insurance fallback if workspace is too small (should not trigger).
__global__ void naive_conv(const float* __restrict__ x, const float* __restrict__ wt,
                           const float* __restrict__ bias, float* __restrict__ y) {
    int w = threadIdx.x;
    int h = blockIdx.x & 127;
    int o = (blockIdx.x >> 7) & 63;
    int b = blockIdx.x >> 13;
    float s = bias[b * 64 + o];
    for (int c = 0; c < 64; ++c)
        for (int i = 0; i < 3; ++i)
            for (int j = 0; j < 3; ++j) {
                int hh = (h + i + 127) & 127;
                int ww = (w + j + 127) & 127;
                s += x[(((size_t)b * 64 + c) * 128 + hh) * 128 + ww] *
                     wt[((size_t)b * 576 + (size_t)(c * 9 + i * 3 + j)) * 64 + o];
            }
    y[(((size_t)b * 64 + o) * 128 + h) * 128 + w] = s;
}

extern "C" void kernel_launch(void* const* d_in, const int* in_sizes, int n_in,
                              void* d_out, int out_size, void* d_ws, size_t ws_size,
                              hipStream_t stream) {
    const float* x    = (const float*)d_in[0];
    const float* wt   = (const float*)d_in[1];
    const float* bias = (const float*)d_in[2];
    float* y = (float*)d_out;

    const size_t WF_ELEMS = (size_t)B_N * 9 * 2 * 4 * 64 * 8;   // 589824
    const size_t WF_BYTES = WF_ELEMS * sizeof(u16);             // 1.18 MB

    if (ws_size >= WF_BYTES) {
        u16* wf = (u16*)d_ws;
        hipLaunchKernelGGL(prep_weights, dim3(288), dim3(256), 0, stream, wt, wf);
        hipLaunchKernelGGL(conv_main, dim3(B_N * H_N / 4), dim3(256), 0, stream, x, wf, bias, y);
    } else {
        hipLaunchKernelGGL(naive_conv, dim3(B_N * O_N * H_N), dim3(128), 0, stream, x, wt, bias, y);
    }
}

// Round 9
// 44.800 us; speedup vs baseline: 1.5403x; 1.5403x over previous
//
#include <hip/hip_runtime.h>
#include <stdint.h>

#define B_N 16
#define C_N 64
#define O_N 64
#define H_N 128
#define W_N 128

typedef short bf16x8 __attribute__((ext_vector_type(8)));
typedef float f32x4 __attribute__((ext_vector_type(4)));
typedef float f32x16 __attribute__((ext_vector_type(16)));
typedef unsigned short u16;
typedef u16 u16x4 __attribute__((ext_vector_type(4)));
typedef u16 u16x8 __attribute__((ext_vector_type(8)));

__device__ __forceinline__ u16 f2bf(float f) {
    uint32_t u = __float_as_uint(f);
    u += 0x7FFFu + ((u >> 16) & 1u);
    return (u16)(u >> 16);
}

// Period-8 swizzle on byte bits 4-6. RULE (R8 lesson): the XOR must be applied
// to the COMPLETE in-row byte offset — adding any c-offset after the XOR can
// carry into bit 7 (the w-row bit) and read the wrong row.
__device__ __forceinline__ int swz(int w) { return (w & 7) << 4; }

// Pre-gather weights into 32x32x16 B-fragment order:
// wf[b][ij][kb][wn][l][j8] (bf16); value = weight[b][c*9+ij][o],
// c = kb*16 + (l>>5)*8 + j8,  o = wn*32 + (l&31).
// (A and B use the IDENTICAL lane->k map, so any k-permutation mismatch vs
// the HW layout cancels in the contraction; C/D layout is the HW-verified one.)
__global__ __launch_bounds__(256) void prep_weights(const float* __restrict__ wt,
                                                    u16* __restrict__ wf) {
    int idx = blockIdx.x * 256 + threadIdx.x;   // 16*9*4*2*64 = 73728 threads
    int e = idx;
    int l  = e & 63; e >>= 6;
    int wn = e & 1;  e >>= 1;
    int kb = e & 3;  e >>= 2;
    int ij = e % 9;
    int b  = e / 9;
    const int o = wn * 32 + (l & 31);
    const int cbase = kb * 16 + (l >> 5) * 8;
    u16x8 pk;
#pragma unroll
    for (int j8 = 0; j8 < 8; ++j8) {
        float v = wt[((size_t)b * 576 + (size_t)(cbase + j8) * 9 + ij) * 64 + o];
        pk[j8] = f2bf(v);
    }
    *reinterpret_cast<u16x8*>(wf + (size_t)idx * 8) = pk;
}

// Main kernel v9b: v9 with the swizzle-carry bug fixed (see swz comment).
// 512 blocks x 256 threads (4 waves), 4-row strip, 64KB LDS -> 2 INDEPENDENT
// blocks/CU (2 waves/SIMD, one from each block: uncorrelated barrier/vmcnt
// stalls — the R6 lockstep diagnosis). Spill discipline: serial prologue
// (max two 32-reg holds live), wreg loaded last; 32x32x16 MFMA
// (wreg[9][4]=144 regs, acc 2x16). Peak ~230 regs < 256 @ (256,2).
__global__ __launch_bounds__(256, 2) void conv_main(const float* __restrict__ x,
                                                    const u16* __restrict__ wf,
                                                    const float* __restrict__ bias,
                                                    float* __restrict__ y) {
    __shared__ u16 xl[4 * 128 * 64];   // 4 slots x [w][c] bf16 = 64 KB, swz

    // XCD-bijective swizzle: 512 wgs, 8 XCDs, chunk 64 -> XCD j owns 2 full b's.
    const int lid = (blockIdx.x & 7) * 64 + (blockIdx.x >> 3);
    const int b   = lid >> 5;
    const int h0  = (lid & 31) * 4;
    const int tid = threadIdx.x;
    const int wid = tid >> 6;
    const int l   = tid & 63;
    const int wave_m = wid >> 1;              // 0..1 -> 64-px band
    const int wave_n = wid & 1;               // 0..1 -> 32-o band
    const int m0 = wave_m * 64;
    const int o0 = wave_n * 32;
    const int l31 = l & 31;
    const int lhi = l >> 5;                   // k-half selector

    // staging task: 32 w-quads x 8 cq2 (2 c-quads each)
    const int w4  = tid & 31;
    const int cq2 = tid >> 5;                 // 0..7
    const float* xb = x + (size_t)b * (64 * 128 * 128);
    const u16* wfb  = wf + (size_t)b * 36864;

    auto ldrow = [&](int s, f32x4* d) {
        int hr = (h0 + s + 127) & 127;        // input row h0 + s - 1 (wrap)
#pragma unroll
        for (int half = 0; half < 2; ++half) {
            const float* src = xb + ((size_t)(cq2 * 2 + half) * 4 * 128 + hr) * 128 + w4 * 4;
            d[half * 4 + 0] = *reinterpret_cast<const f32x4*>(src);
            d[half * 4 + 1] = *reinterpret_cast<const f32x4*>(src + 16384);
            d[half * 4 + 2] = *reinterpret_cast<const f32x4*>(src + 32768);
            d[half * 4 + 3] = *reinterpret_cast<const f32x4*>(src + 49152);
        }
    };
    auto wrrow = [&](int slot, const f32x4* d) {
#pragma unroll
        for (int half = 0; half < 2; ++half) {
            const int cq = cq2 * 2 + half;
#pragma unroll
            for (int j = 0; j < 4; ++j) {
                int w = w4 * 4 + j;
                u16x4 pk;
                pk.x = f2bf(d[half * 4 + 0][j]); pk.y = f2bf(d[half * 4 + 1][j]);
                pk.z = f2bf(d[half * 4 + 2][j]); pk.w = f2bf(d[half * 4 + 3][j]);
                int byte = slot * 16384 + w * 128 + ((cq * 8) ^ swz(w));
                *reinterpret_cast<u16x4*>(reinterpret_cast<char*>(xl) + byte) = pk;
            }
        }
    };

    // ---- Prologue, pressure-disciplined: two holds only; wreg LAST ----
    f32x4 stA[8], stB[8];
    ldrow(0, stA); ldrow(1, stB);
    wrrow(0, stA);
    ldrow(2, stA);
    wrrow(1, stB);
    ldrow(3, stB);                            // stB holds s=3 into the loop
    wrrow(2, stA);

    bf16x8 wreg[9][4];                        // [ij][kb] = 144 VGPRs
#pragma unroll
    for (int ij = 0; ij < 9; ++ij)
#pragma unroll
        for (int kb = 0; kb < 4; ++kb)
            wreg[ij][kb] = *reinterpret_cast<const bf16x8*>(
                wfb + (size_t)(((ij * 4 + kb) * 2 + wave_n) * 64 + l) * 8);

    const float bv = bias[b * 64 + o0 + l31];
    __syncthreads();

    // ---- 4 output rows. Row r reads s=r..r+2 (slots s&3); restage:
    //      wrrow s=r+3 -> slot (r+3)&3 at ij2 (data from last row's ldrow),
    //      ldrow s=r+4 at ij5. Barrier after each row (syncs only 4 waves).
#pragma unroll
    for (int r = 0; r < 4; ++r) {
        f32x16 acc[2];
        acc[0] = (f32x16)(0.f);
        acc[1] = (f32x16)(0.f);

#pragma unroll
        for (int ij = 0; ij < 9; ++ij) {
            if (ij == 2 && r < 3) wrrow((r + 3) & 3, stB);
            if (ij == 5 && r < 2) ldrow(r + 4, stB);

            const int i = ij / 3;
            const int jsh = ij % 3 - 1;
            const int rbase = ((r + i) & 3) * 16384;
#pragma unroll
            for (int mf = 0; mf < 2; ++mf) {
                int w = (m0 + mf * 32 + l31 + jsh + 128) & 127;
                const char* base = reinterpret_cast<const char*>(xl) + rbase + w * 128;
                const int boff = (lhi * 16) ^ swz(w);   // full offset XORed; kb
                                                        // flips disjoint bits 5-6
#pragma unroll
                for (int kb = 0; kb < 4; ++kb) {
                    bf16x8 afr = *reinterpret_cast<const bf16x8*>(base + (boff ^ (kb * 32)));
                    acc[mf] = __builtin_amdgcn_mfma_f32_32x32x16_bf16(
                        afr, wreg[ij][kb], acc[mf], 0, 0, 0);
                }
            }
        }

        // ---- Epilogue: D 32x32 layout col(o)=l&31, row(w)=(reg&3)+8*(reg>>2)+4*lhi
        const int h = h0 + r;
        const int o = o0 + l31;
        float* dstb = y + (((size_t)b * 64 + o) * 128 + h) * 128;
#pragma unroll
        for (int mf = 0; mf < 2; ++mf) {
#pragma unroll
            for (int g = 0; g < 4; ++g) {
                int w0 = m0 + mf * 32 + g * 8 + lhi * 4;
                f32x4 out;
                out[0] = acc[mf][g * 4 + 0] + bv;
                out[1] = acc[mf][g * 4 + 1] + bv;
                out[2] = acc[mf][g * 4 + 2] + bv;
                out[3] = acc[mf][g * 4 + 3] + bv;
                *reinterpret_cast<f32x4*>(dstb + w0) = out;
            }
        }
        if (r < 3) __syncthreads();
    }
}

// Correctness-insurance fallback if workspace is too small (should not trigger).
__global__ void naive_conv(const float* __restrict__ x, const float* __restrict__ wt,
                           const float* __restrict__ bias, float* __restrict__ y) {
    int w = threadIdx.x;
    int h = blockIdx.x & 127;
    int o = (blockIdx.x >> 7) & 63;
    int b = blockIdx.x >> 13;
    float s = bias[b * 64 + o];
    for (int c = 0; c < 64; ++c)
        for (int i = 0; i < 3; ++i)
            for (int j = 0; j < 3; ++j) {
                int hh = (h + i + 127) & 127;
                int ww = (w + j + 127) & 127;
                s += x[(((size_t)b * 64 + c) * 128 + hh) * 128 + ww] *
                     wt[((size_t)b * 576 + (size_t)(c * 9 + i * 3 + j)) * 64 + o];
            }
    y[(((size_t)b * 64 + o) * 128 + h) * 128 + w] = s;
}

extern "C" void kernel_launch(void* const* d_in, const int* in_sizes, int n_in,
                              void* d_out, int out_size, void* d_ws, size_t ws_size,
                              hipStream_t stream) {
    const float* x    = (const float*)d_in[0];
    const float* wt   = (const float*)d_in[1];
    const float* bias = (const float*)d_in[2];
    float* y = (float*)d_out;

    const size_t WF_ELEMS = (size_t)B_N * 9 * 4 * 2 * 64 * 8;   // 589824
    const size_t WF_BYTES = WF_ELEMS * sizeof(u16);             // 1.18 MB

    if (ws_size >= WF_BYTES) {
        u16* wf = (u16*)d_ws;
        hipLaunchKernelGGL(prep_weights, dim3(288), dim3(256), 0, stream, wt, wf);
        hipLaunchKernelGGL(conv_main, dim3(B_N * H_N / 4), dim3(256), 0, stream, x, wf, bias, y);
    } else {
        hipLaunchKernelGGL(naive_conv, dim3(B_N * O_N * H_N), dim3(128), 0, stream, x, wt, bias, y);
    }
}

// Round 10
// 37.148 us; speedup vs baseline: 1.8576x; 1.2060x over previous
//
#include <hip/hip_runtime.h>
#include <stdint.h>

#define B_N 16
#define C_N 64
#define O_N 64
#define H_N 128
#define W_N 128

typedef short bf16x8 __attribute__((ext_vector_type(8)));
typedef float f32x4 __attribute__((ext_vector_type(4)));
typedef unsigned short u16;
typedef u16 u16x4 __attribute__((ext_vector_type(4)));
typedef u16 u16x8 __attribute__((ext_vector_type(8)));

__device__ __forceinline__ u16 f2bf(float f) {
    uint32_t u = __float_as_uint(f);
    u += 0x7FFFu + ((u >> 16) & 1u);
    return (u16)(u >> 16);
}

// Period-8 swizzle: conflict-free b128 reads on every 8-w window (incl. the
// jsh=+-1 shifted windows). Staging writes pay ~28 cyc/store (R0/R1 ledger)
// — accepted (LDS pipe not the bottleneck; R4->R5 flatness proved it).
// RULE (R8): XOR the COMPLETE in-row offset — adds after the XOR can carry
// into the w-row bit.
__device__ __forceinline__ int swz(int w) { return (w & 7) << 4; }

// Pre-gather weights into exact B-fragment order, COALESCED (R7-verified):
// thread owns a full j8-row -> one b128 store (old version: 4 scattered u16).
// wf[b][ij][cs][of][l][j8] (bf16); value = weight[b][c*9+ij][o],
// c = cs*32 + (l>>4)*8 + j8,  o = of*16 + (l&15).
__global__ __launch_bounds__(256) void prep_weights(const float* __restrict__ wt,
                                                    u16* __restrict__ wf) {
    int idx = blockIdx.x * 256 + threadIdx.x;   // 16*9*2*4*64 = 73728 threads
    int e = idx;
    int l  = e & 63; e >>= 6;
    int of = e & 3;  e >>= 2;
    int cs = e & 1;  e >>= 1;
    int ij = e % 9;
    int b  = e / 9;
    const int o = of * 16 + (l & 15);
    const int cbase = cs * 32 + (l >> 4) * 8;
    u16x8 pk;
#pragma unroll
    for (int j8 = 0; j8 < 8; ++j8) {
        float v = wt[((size_t)b * 576 + (size_t)(cbase + j8) * 9 + ij) * 64 + o];
        pk[j8] = f2bf(v);
    }
    *reinterpret_cast<u16x8*>(wf + (size_t)idx * 8) = pk;
}

// Main kernel v7 (champion, 38.3us): 8-row strips, grid 256, 512 thr (8
// waves x 32px x 32o), wreg B-frags in registers (144, lands in AGPRs),
// deep staging pipeline:
//  - 6 LDS row-slots (96 KB; 1 block/CU, 2 waves/SIMD).
//  - Row r: ds_write s=r+4 at ij0 (data loaded during row r-1), global_load
//    s=r+5 at ij3. Barrier every 2 rows (write->read distance >=2 both ways).
// Session ledger: deeper pipelines (R6), fewer barriers (R6), more waves
// (R3), independent-block stagger (R9) all flat-to-negative -> this is the
// latency plateau of the structure; only prep_weights polished this round.
__global__ __launch_bounds__(512, 2) void conv_main(const float* __restrict__ x,
                                                    const u16* __restrict__ wf,
                                                    const float* __restrict__ bias,
                                                    float* __restrict__ y) {
    __shared__ u16 xl[6 * 128 * 64];   // 6 slots x [w][c] bf16 = 96 KB, swz

    // XCD-bijective swizzle: 256 wgs, 8 XCDs, chunk 32 -> XCD j owns 2 full b's.
    const int lid = (blockIdx.x & 7) * 32 + (blockIdx.x >> 3);
    const int b   = lid >> 4;
    const int h0  = (lid & 15) * 8;
    const int tid = threadIdx.x;
    const int wid = tid >> 6;
    const int l   = tid & 63;
    const int wave_m = wid >> 1;              // 0..3 -> 32-px band
    const int wave_n = wid & 1;               // 0..1 -> 32-o band
    const int m0 = wave_m * 32;
    const int o0 = wave_n * 32;
    const int lr = l & 15;
    const int lg = l >> 4;

    // staging task: 32 w-quads x 16 c-quads = 512 threads, full row per pass
    const int w4 = tid & 31;
    const int cq = tid >> 5;                  // 0..15
    const float* xb = x + (size_t)b * (64 * 128 * 128);
    const u16* wfb  = wf + (size_t)b * 36864;

    auto ldrow = [&](int s, f32x4* d) {
        int hr = (h0 + s + 127) & 127;        // input row h0 + s - 1 (wrap)
        const float* src = xb + ((size_t)cq * 4 * 128 + hr) * 128 + w4 * 4;
        d[0] = *reinterpret_cast<const f32x4*>(src);
        d[1] = *reinterpret_cast<const f32x4*>(src + 16384);
        d[2] = *reinterpret_cast<const f32x4*>(src + 32768);
        d[3] = *reinterpret_cast<const f32x4*>(src + 49152);
    };
    auto wrrow = [&](int slot, const f32x4* d) {   // slot = staged-row % 6
#pragma unroll
        for (int j = 0; j < 4; ++j) {
            int w = w4 * 4 + j;
            u16x4 pk;
            pk.x = f2bf(d[0][j]); pk.y = f2bf(d[1][j]);
            pk.z = f2bf(d[2][j]); pk.w = f2bf(d[3][j]);
            int byte = slot * 16384 + w * 128 + ((cq * 8) ^ swz(w));
            *reinterpret_cast<u16x4*>(reinterpret_cast<char*>(xl) + byte) = pk;
        }
    };

    // ---- Prologue: x loads FIRST, then weights (vmcnt-expressible order),
    //      stage s=0..3 into slots 0..3, preload s=4 into regs ----
    f32x4 s0[4], s1[4], s2[4], st[4];
    ldrow(0, s0); ldrow(1, s1); ldrow(2, s2);

    bf16x8 wreg[9][2][2];                     // [ij][cs][nf] = 144 regs (AGPRs)
#pragma unroll
    for (int ij = 0; ij < 9; ++ij)
#pragma unroll
        for (int cs = 0; cs < 2; ++cs)
#pragma unroll
            for (int nf = 0; nf < 2; ++nf)
                wreg[ij][cs][nf] = *reinterpret_cast<const bf16x8*>(
                    wfb + (size_t)(((ij * 2 + cs) * 4 + wave_n * 2 + nf) * 64 + l) * 8);

    const float bv0 = bias[b * 64 + o0 + lr];
    const float bv1 = bias[b * 64 + o0 + 16 + lr];

    wrrow(0, s0); wrrow(1, s1); wrrow(2, s2);
    ldrow(3, s0); ldrow(4, st);               // s4 stays in regs for row 0
    wrrow(3, s0);
    __syncthreads();

    // ---- 8 output rows; row r reads slots (r..r+2)%6 ----
    int slA = 0;                              // r % 6, tracked incrementally
#pragma unroll 1
    for (int r = 0; r < 8; ++r) {
        const int slB = (slA + 1 == 6) ? 0 : slA + 1;
        const int slC = (slB + 1 == 6) ? 0 : slB + 1;
        const int slW = (slC + 2 >= 6) ? slC + 2 - 6 : slC + 2;   // (r+4)%6
        const int base0 = slA * 16384, base1 = slB * 16384, base2 = slC * 16384;

        f32x4 acc[2][2];
#pragma unroll
        for (int mf = 0; mf < 2; ++mf)
#pragma unroll
            for (int nf = 0; nf < 2; ++nf)
                acc[mf][nf] = (f32x4){0.f, 0.f, 0.f, 0.f};

#pragma unroll
        for (int ij = 0; ij < 9; ++ij) {
            if (ij == 0 && r < 6) wrrow(slW, st);     // data loaded last row
            if (ij == 3 && r < 5) ldrow(r + 5, st);   // consumed next row

            const int i = ij / 3;
            const int jsh = ij % 3 - 1;
            const int rbase = (i == 0) ? base0 : (i == 1) ? base1 : base2;
#pragma unroll
            for (int cs = 0; cs < 2; ++cs) {
                const int cb = cs * 64 + lg * 16;
                bf16x8 afr[2];
#pragma unroll
                for (int mf = 0; mf < 2; ++mf) {
                    int w = (m0 + mf * 16 + lr + jsh + 128) & 127;
                    int byte = rbase + w * 128 + (cb ^ swz(w));
                    afr[mf] = *reinterpret_cast<const bf16x8*>(
                        reinterpret_cast<const char*>(xl) + byte);
                }
#pragma unroll
                for (int mf = 0; mf < 2; ++mf) {
                    acc[mf][0] = __builtin_amdgcn_mfma_f32_16x16x32_bf16(afr[mf], wreg[ij][cs][0], acc[mf][0], 0, 0, 0);
                    acc[mf][1] = __builtin_amdgcn_mfma_f32_16x16x32_bf16(afr[mf], wreg[ij][cs][1], acc[mf][1], 0, 0, 0);
                }
            }
        }

        // ---- Epilogue: D layout col=lane&15 (o), row=(lane>>4)*4+reg (w) ----
        const int h = h0 + r;
#pragma unroll
        for (int nf = 0; nf < 2; ++nf) {
            int o = o0 + nf * 16 + lr;
            float bv = nf ? bv1 : bv0;
#pragma unroll
            for (int mf = 0; mf < 2; ++mf) {
                int w0 = m0 + mf * 16 + lg * 4;
                float* dst = y + (((size_t)b * 64 + o) * 128 + h) * 128 + w0;
                f32x4 out;
                out[0] = acc[mf][nf][0] + bv;
                out[1] = acc[mf][nf][1] + bv;
                out[2] = acc[mf][nf][2] + bv;
                out[3] = acc[mf][nf][3] + bv;
                *reinterpret_cast<f32x4*>(dst) = out;
            }
        }

        // Barrier every 2 rows (after rows 1,3,5). Hazard ledger: a slot
        // written at row r is first read at row r+2 and last-read-before-
        // overwrite at row r-2 -> one barrier inside each 2-row window in
        // both directions suffices (checked per slot for r=0..7).
        if ((r & 1) && r < 7) __syncthreads();
        slA = slB;
    }
}

// Correctness-insurance fallback if workspace is too small (should not trigger).
__global__ void naive_conv(const float* __restrict__ x, const float* __restrict__ wt,
                           const float* __restrict__ bias, float* __restrict__ y) {
    int w = threadIdx.x;
    int h = blockIdx.x & 127;
    int o = (blockIdx.x >> 7) & 63;
    int b = blockIdx.x >> 13;
    float s = bias[b * 64 + o];
    for (int c = 0; c < 64; ++c)
        for (int i = 0; i < 3; ++i)
            for (int j = 0; j < 3; ++j) {
                int hh = (h + i + 127) & 127;
                int ww = (w + j + 127) & 127;
                s += x[(((size_t)b * 64 + c) * 128 + hh) * 128 + ww] *
                     wt[((size_t)b * 576 + (size_t)(c * 9 + i * 3 + j)) * 64 + o];
            }
    y[(((size_t)b * 64 + o) * 128 + h) * 128 + w] = s;
}

extern "C" void kernel_launch(void* const* d_in, const int* in_sizes, int n_in,
                              void* d_out, int out_size, void* d_ws, size_t ws_size,
                              hipStream_t stream) {
    const float* x    = (const float*)d_in[0];
    const float* wt   = (const float*)d_in[1];
    const float* bias = (const float*)d_in[2];
    float* y = (float*)d_out;

    const size_t WF_ELEMS = (size_t)B_N * 9 * 2 * 4 * 64 * 8;   // 589824
    const size_t WF_BYTES = WF_ELEMS * sizeof(u16);             // 1.18 MB

    if (ws_size >= WF_BYTES) {
        u16* wf = (u16*)d_ws;
        hipLaunchKernelGGL(prep_weights, dim3(288), dim3(256), 0, stream, wt, wf);
        hipLaunchKernelGGL(conv_main, dim3(B_N * H_N / 8), dim3(512), 0, stream, x, wf, bias, y);
    } else {
        hipLaunchKernelGGL(naive_conv, dim3(B_N * O_N * H_N), dim3(128), 0, stream, x, wt, bias, y);
    }
}

// Round 11
// 37.106 us; speedup vs baseline: 1.8596x; 1.0011x over previous
//
#include <hip/hip_runtime.h>
#include <stdint.h>

#define B_N 16
#define C_N 64
#define O_N 64
#define H_N 128
#define W_N 128

typedef short bf16x8 __attribute__((ext_vector_type(8)));
typedef float f32x4 __attribute__((ext_vector_type(4)));
typedef unsigned short u16;
typedef u16 u16x4 __attribute__((ext_vector_type(4)));

__device__ __forceinline__ u16 f2bf(float f) {
    uint32_t u = __float_as_uint(f);
    u += 0x7FFFu + ((u >> 16) & 1u);
    return (u16)(u >> 16);
}

// Period-8 swizzle: conflict-free b128 reads on every 8-w window (incl. the
// jsh=+-1 shifted windows). Staging writes pay ~28 cyc/store (R0/R1 ledger)
// — accepted (LDS pipe not the bottleneck; R4->R5 flatness proved it).
// RULE (R8): XOR the COMPLETE in-row offset — adds after the XOR can carry
// into the w-row bit.
__device__ __forceinline__ int swz(int w) { return (w & 7) << 4; }

// Main kernel v10 = v7 champion chassis + FUSED weight transform (prep
// dispatch eliminated; R10 ledger: prep + inter-dispatch drain ~= 5.6us of
// pure serialization).
// Chassis: 8-row strips, grid 256, 512 thr (8 waves x 32px x 32o), wreg
// B-frags in registers (144, AGPR-side), 6 LDS row-slots (96 KB; 1 block/CU,
// 2 waves/SIMD), restage s=r+4 write at ij0 / s=r+5 load at ij3, barrier
// every 2 rows. Session ledger: deeper pipelines (R6), fewer barriers (R6),
// more waves (R3), wave-split (R3), block-stagger (R9) all flat-to-negative.
// Fused ingest: block reads its b's fp32 weight slice COALESCED (18 x f32x4
// per thread), converts, scatters bf16 into x-slot LDS (72 KB scratch, before
// x staging), waves ds_read_b128 their 36 fragments, then LDS is recycled.
// 16 blocks per b are XCD-colocated by the swizzle -> slice is HBM-read once
// per XCD, L2-served to the rest.
__global__ __launch_bounds__(512, 2) void conv_main(const float* __restrict__ x,
                                                    const float* __restrict__ wt,
                                                    const float* __restrict__ bias,
                                                    float* __restrict__ y) {
    __shared__ u16 xl[6 * 128 * 64];   // 6 slots x [w][c] bf16 = 96 KB, swz

    // XCD-bijective swizzle: 256 wgs, 8 XCDs, chunk 32 -> XCD j owns 2 full b's.
    const int lid = (blockIdx.x & 7) * 32 + (blockIdx.x >> 3);
    const int b   = lid >> 4;
    const int h0  = (lid & 15) * 8;
    const int tid = threadIdx.x;
    const int wid = tid >> 6;
    const int l   = tid & 63;
    const int wave_m = wid >> 1;              // 0..3 -> 32-px band
    const int wave_n = wid & 1;               // 0..1 -> 32-o band
    const int m0 = wave_m * 32;
    const int o0 = wave_n * 32;
    const int lr = l & 15;
    const int lg = l >> 4;

    // staging task: 32 w-quads x 16 c-quads = 512 threads, full row per pass
    const int w4 = tid & 31;
    const int cq = tid >> 5;                  // 0..15
    const float* xb  = x  + (size_t)b * (64 * 128 * 128);
    const float* wtb = wt + (size_t)b * (576 * 64);

    auto ldrow = [&](int s, f32x4* d) {
        int hr = (h0 + s + 127) & 127;        // input row h0 + s - 1 (wrap)
        const float* src = xb + ((size_t)cq * 4 * 128 + hr) * 128 + w4 * 4;
        d[0] = *reinterpret_cast<const f32x4*>(src);
        d[1] = *reinterpret_cast<const f32x4*>(src + 16384);
        d[2] = *reinterpret_cast<const f32x4*>(src + 32768);
        d[3] = *reinterpret_cast<const f32x4*>(src + 49152);
    };
    auto wrrow = [&](int slot, const f32x4* d) {   // slot = staged-row % 6
#pragma unroll
        for (int j = 0; j < 4; ++j) {
            int w = w4 * 4 + j;
            u16x4 pk;
            pk.x = f2bf(d[0][j]); pk.y = f2bf(d[1][j]);
            pk.z = f2bf(d[2][j]); pk.w = f2bf(d[3][j]);
            int byte = slot * 16384 + w * 128 + ((cq * 8) ^ swz(w));
            *reinterpret_cast<u16x4*>(reinterpret_cast<char*>(xl) + byte) = pk;
        }
    };

    // ---- Fused weight ingest: fp32 slice -> bf16 fragment order in LDS.
    //      Task (c, ij, o4): f32x4 coalesced read (consecutive tid -> o4 ->
    //      contiguous), 4 scattered u16 LDS writes. Mapping identical to the
    //      R7/R10-verified prep: c = cs*32 + lgc*8 + j8, o = of*16 + lrc.
    u16* wl = xl;                             // 36864 u16 = 72 KB scratch
#pragma unroll
    for (int it = 0; it < 18; ++it) {
        int task = it * 512 + tid;            // < 9216 = 64c * 9ij * 16o4
        int o4 = task & 15;
        int t2 = task >> 4;
        int ij = t2 % 9;
        int c  = t2 / 9;
        f32x4 v = *reinterpret_cast<const f32x4*>(wtb + ((size_t)c * 9 + ij) * 64 + o4 * 4);
        const int cs = c >> 5, lgc = (c >> 3) & 3, j8 = c & 7;
#pragma unroll
        for (int k = 0; k < 4; ++k) {
            int o = o4 * 4 + k;
            int of = o >> 4, lrc = o & 15;
            wl[(((ij * 2 + cs) * 4 + of) * 64 + lgc * 16 + lrc) * 8 + j8] = f2bf(v[k]);
        }
    }

    // x rows 0..2 issued now: latency hides under the ingest tail + barriers
    f32x4 s0[4], s1[4], s2[4], st[4];
    ldrow(0, s0); ldrow(1, s1); ldrow(2, s2);
    __syncthreads();                          // wl fully written

    bf16x8 wreg[9][2][2];                     // [ij][cs][nf] = 144 regs
#pragma unroll
    for (int ij = 0; ij < 9; ++ij)
#pragma unroll
        for (int cs = 0; cs < 2; ++cs)
#pragma unroll
            for (int nf = 0; nf < 2; ++nf)
                wreg[ij][cs][nf] = *reinterpret_cast<const bf16x8*>(
                    wl + (size_t)(((ij * 2 + cs) * 4 + wave_n * 2 + nf) * 64 + l) * 8);

    const float bv0 = bias[b * 64 + o0 + lr];
    const float bv1 = bias[b * 64 + o0 + 16 + lr];
    __syncthreads();                          // wreg reads done; recycle LDS

    // ---- Prologue staging: slots 0..3, s=4 held in regs for row 0 ----
    wrrow(0, s0); wrrow(1, s1); wrrow(2, s2);
    ldrow(3, s0); ldrow(4, st);
    wrrow(3, s0);
    __syncthreads();

    // ---- 8 output rows; row r reads slots (r..r+2)%6 ----
    int slA = 0;                              // r % 6, tracked incrementally
#pragma unroll 1
    for (int r = 0; r < 8; ++r) {
        const int slB = (slA + 1 == 6) ? 0 : slA + 1;
        const int slC = (slB + 1 == 6) ? 0 : slB + 1;
        const int slW = (slC + 2 >= 6) ? slC + 2 - 6 : slC + 2;   // (r+4)%6
        const int base0 = slA * 16384, base1 = slB * 16384, base2 = slC * 16384;

        f32x4 acc[2][2];
#pragma unroll
        for (int mf = 0; mf < 2; ++mf)
#pragma unroll
            for (int nf = 0; nf < 2; ++nf)
                acc[mf][nf] = (f32x4){0.f, 0.f, 0.f, 0.f};

#pragma unroll
        for (int ij = 0; ij < 9; ++ij) {
            if (ij == 0 && r < 6) wrrow(slW, st);     // data loaded last row
            if (ij == 3 && r < 5) ldrow(r + 5, st);   // consumed next row

            const int i = ij / 3;
            const int jsh = ij % 3 - 1;
            const int rbase = (i == 0) ? base0 : (i == 1) ? base1 : base2;
#pragma unroll
            for (int cs = 0; cs < 2; ++cs) {
                const int cb = cs * 64 + lg * 16;
                bf16x8 afr[2];
#pragma unroll
                for (int mf = 0; mf < 2; ++mf) {
                    int w = (m0 + mf * 16 + lr + jsh + 128) & 127;
                    int byte = rbase + w * 128 + (cb ^ swz(w));
                    afr[mf] = *reinterpret_cast<const bf16x8*>(
                        reinterpret_cast<const char*>(xl) + byte);
                }
#pragma unroll
                for (int mf = 0; mf < 2; ++mf) {
                    acc[mf][0] = __builtin_amdgcn_mfma_f32_16x16x32_bf16(afr[mf], wreg[ij][cs][0], acc[mf][0], 0, 0, 0);
                    acc[mf][1] = __builtin_amdgcn_mfma_f32_16x16x32_bf16(afr[mf], wreg[ij][cs][1], acc[mf][1], 0, 0, 0);
                }
            }
        }

        // ---- Epilogue: D layout col=lane&15 (o), row=(lane>>4)*4+reg (w) ----
        const int h = h0 + r;
#pragma unroll
        for (int nf = 0; nf < 2; ++nf) {
            int o = o0 + nf * 16 + lr;
            float bv = nf ? bv1 : bv0;
#pragma unroll
            for (int mf = 0; mf < 2; ++mf) {
                int w0 = m0 + mf * 16 + lg * 4;
                float* dst = y + (((size_t)b * 64 + o) * 128 + h) * 128 + w0;
                f32x4 out;
                out[0] = acc[mf][nf][0] + bv;
                out[1] = acc[mf][nf][1] + bv;
                out[2] = acc[mf][nf][2] + bv;
                out[3] = acc[mf][nf][3] + bv;
                *reinterpret_cast<f32x4*>(dst) = out;
            }
        }

        // Barrier every 2 rows (after rows 1,3,5). Hazard ledger: a slot
        // written at row r is first read at row r+2 and last-read-before-
        // overwrite at row r-2 -> one barrier inside each 2-row window in
        // both directions suffices (checked per slot for r=0..7).
        if ((r & 1) && r < 7) __syncthreads();
        slA = slB;
    }
}

extern "C" void kernel_launch(void* const* d_in, const int* in_sizes, int n_in,
                              void* d_out, int out_size, void* d_ws, size_t ws_size,
                              hipStream_t stream) {
    const float* x    = (const float*)d_in[0];
    const float* wt   = (const float*)d_in[1];
    const float* bias = (const float*)d_in[2];
    float* y = (float*)d_out;
    (void)d_ws; (void)ws_size;                // fused kernel needs no workspace

    hipLaunchKernelGGL(conv_main, dim3(B_N * H_N / 8), dim3(512), 0, stream,
                       x, wt, bias, y);
}

// Round 12
// 32.580 us; speedup vs baseline: 2.1180x; 1.1389x over previous
//
#include <hip/hip_runtime.h>
#include <stdint.h>

#define B_N 16
#define C_N 64
#define O_N 64
#define H_N 128
#define W_N 128

typedef short bf16x8 __attribute__((ext_vector_type(8)));
typedef float f32x4 __attribute__((ext_vector_type(4)));
typedef unsigned short u16;
typedef u16 u16x4 __attribute__((ext_vector_type(4)));
typedef u16 u16x8 __attribute__((ext_vector_type(8)));

__device__ __forceinline__ u16 f2bf(float f) {
    uint32_t u = __float_as_uint(f);
    u += 0x7FFFu + ((u >> 16) & 1u);
    return (u16)(u >> 16);
}

// Period-8 swizzle: conflict-free b128 reads on every 8-w window (incl. the
// jsh=+-1 shifted windows). Staging writes pay ~28 cyc/store (R0/R1 ledger)
// — accepted (LDS pipe not the bottleneck; R4->R5 flatness proved it).
// RULE (R8): XOR the COMPLETE in-row offset — adds after the XOR can carry
// into the w-row bit.
__device__ __forceinline__ int swz(int w) { return (w & 7) << 4; }

// Main kernel v12 = v10 fused chassis with the ingest ORIENTATION FIXED.
// R11 lesson: coalesced-read + scattered-u16-LDS-write ingest added 4.4M
// bank-conflict cycles in the serial prologue (+~5us) — exactly cancelling
// the eliminated prep dispatch. This version ports R10's proven prep
// orientation INTO the kernel: strided dword reads (64B-segment coalesced,
// L2-served after first block per XCD) + ONE linear ds_write_b128 per
// thread per iter (conflict-free). x-row loads issued BEFORE ingest so HBM
// latency hides under it.
// Chassis (unchanged, champion): 8-row strips, grid 256, 512 thr (8 waves x
// 32px x 32o), wreg B-frags in registers (144), 6 LDS row-slots (96 KB;
// 1 block/CU, 2 waves/SIMD), restage s=r+4 at ij0 / load s=r+5 at ij3,
// barrier every 2 rows. Ledger: deeper pipelines (R6), fewer barriers (R6),
// more waves (R3), wave-split (R3), block-stagger (R9) all flat-to-negative.
__global__ __launch_bounds__(512, 2) void conv_main(const float* __restrict__ x,
                                                    const float* __restrict__ wt,
                                                    const float* __restrict__ bias,
                                                    float* __restrict__ y) {
    __shared__ u16 xl[6 * 128 * 64];   // 6 slots x [w][c] bf16 = 96 KB, swz

    // XCD-bijective swizzle: 256 wgs, 8 XCDs, chunk 32 -> XCD j owns 2 full b's.
    const int lid = (blockIdx.x & 7) * 32 + (blockIdx.x >> 3);
    const int b   = lid >> 4;
    const int h0  = (lid & 15) * 8;
    const int tid = threadIdx.x;
    const int wid = tid >> 6;
    const int l   = tid & 63;
    const int wave_m = wid >> 1;              // 0..3 -> 32-px band
    const int wave_n = wid & 1;               // 0..1 -> 32-o band
    const int m0 = wave_m * 32;
    const int o0 = wave_n * 32;
    const int lr = l & 15;
    const int lg = l >> 4;

    // staging task: 32 w-quads x 16 c-quads = 512 threads, full row per pass
    const int w4 = tid & 31;
    const int cq = tid >> 5;                  // 0..15
    const float* xb  = x  + (size_t)b * (64 * 128 * 128);
    const float* wtb = wt + (size_t)b * (576 * 64);

    auto ldrow = [&](int s, f32x4* d) {
        int hr = (h0 + s + 127) & 127;        // input row h0 + s - 1 (wrap)
        const float* src = xb + ((size_t)cq * 4 * 128 + hr) * 128 + w4 * 4;
        d[0] = *reinterpret_cast<const f32x4*>(src);
        d[1] = *reinterpret_cast<const f32x4*>(src + 16384);
        d[2] = *reinterpret_cast<const f32x4*>(src + 32768);
        d[3] = *reinterpret_cast<const f32x4*>(src + 49152);
    };
    auto wrrow = [&](int slot, const f32x4* d) {   // slot = staged-row % 6
#pragma unroll
        for (int j = 0; j < 4; ++j) {
            int w = w4 * 4 + j;
            u16x4 pk;
            pk.x = f2bf(d[0][j]); pk.y = f2bf(d[1][j]);
            pk.z = f2bf(d[2][j]); pk.w = f2bf(d[3][j]);
            int byte = slot * 16384 + w * 128 + ((cq * 8) ^ swz(w));
            *reinterpret_cast<u16x4*>(reinterpret_cast<char*>(xl) + byte) = pk;
        }
    };

    // ---- x rows 0..2 issued FIRST: HBM latency hides under the ingest ----
    f32x4 s0[4], s1[4], s2[4], st[4];
    ldrow(0, s0); ldrow(1, s1); ldrow(2, s2);

    // ---- Fused weight ingest, prep-orientation (R10-verified mapping):
    //      thread owns fragment-slot idx = ((ij*2+cs)*4+of)*64 + l per iter;
    //      8 strided dword reads (c = cs*32 + (l>>4)*8 + j8, o = of*16+(l&15)),
    //      pack u16x8, ONE linear ds_write_b128 at idx*16 (conflict-free).
    u16* wl = xl;                             // 36864 u16 = 72 KB scratch
#pragma unroll
    for (int it = 0; it < 9; ++it) {
        int task = it * 512 + tid;            // < 4608 = 9ij * 2cs * 4of * 64l
        int tl = task & 63;
        int of = (task >> 6) & 3;
        int cs = (task >> 8) & 1;
        int ij = task >> 9;                   // 0..8
        const int o = of * 16 + (tl & 15);
        const int cbase = cs * 32 + (tl >> 4) * 8;
        u16x8 pk;
#pragma unroll
        for (int j8 = 0; j8 < 8; ++j8) {
            float v = wtb[(size_t)(cbase + j8) * 9 * 64 + (size_t)ij * 64 + o];
            pk[j8] = f2bf(v);
        }
        *reinterpret_cast<u16x8*>(wl + (size_t)task * 8) = pk;
    }
    __syncthreads();                          // wl fully written

    bf16x8 wreg[9][2][2];                     // [ij][cs][nf] = 144 regs
#pragma unroll
    for (int ij = 0; ij < 9; ++ij)
#pragma unroll
        for (int cs = 0; cs < 2; ++cs)
#pragma unroll
            for (int nf = 0; nf < 2; ++nf)
                wreg[ij][cs][nf] = *reinterpret_cast<const bf16x8*>(
                    wl + (size_t)(((ij * 2 + cs) * 4 + wave_n * 2 + nf) * 64 + l) * 8);

    const float bv0 = bias[b * 64 + o0 + lr];
    const float bv1 = bias[b * 64 + o0 + 16 + lr];
    __syncthreads();                          // wreg reads done; recycle LDS

    // ---- Prologue staging: slots 0..3, s=4 held in regs for row 0 ----
    wrrow(0, s0); wrrow(1, s1); wrrow(2, s2);
    ldrow(3, s0); ldrow(4, st);
    wrrow(3, s0);
    __syncthreads();

    // ---- 8 output rows; row r reads slots (r..r+2)%6 ----
    int slA = 0;                              // r % 6, tracked incrementally
#pragma unroll 1
    for (int r = 0; r < 8; ++r) {
        const int slB = (slA + 1 == 6) ? 0 : slA + 1;
        const int slC = (slB + 1 == 6) ? 0 : slB + 1;
        const int slW = (slC + 2 >= 6) ? slC + 2 - 6 : slC + 2;   // (r+4)%6
        const int base0 = slA * 16384, base1 = slB * 16384, base2 = slC * 16384;

        f32x4 acc[2][2];
#pragma unroll
        for (int mf = 0; mf < 2; ++mf)
#pragma unroll
            for (int nf = 0; nf < 2; ++nf)
                acc[mf][nf] = (f32x4){0.f, 0.f, 0.f, 0.f};

#pragma unroll
        for (int ij = 0; ij < 9; ++ij) {
            if (ij == 0 && r < 6) wrrow(slW, st);     // data loaded last row
            if (ij == 3 && r < 5) ldrow(r + 5, st);   // consumed next row

            const int i = ij / 3;
            const int jsh = ij % 3 - 1;
            const int rbase = (i == 0) ? base0 : (i == 1) ? base1 : base2;
#pragma unroll
            for (int cs = 0; cs < 2; ++cs) {
                const int cb = cs * 64 + lg * 16;
                bf16x8 afr[2];
#pragma unroll
                for (int mf = 0; mf < 2; ++mf) {
                    int w = (m0 + mf * 16 + lr + jsh + 128) & 127;
                    int byte = rbase + w * 128 + (cb ^ swz(w));
                    afr[mf] = *reinterpret_cast<const bf16x8*>(
                        reinterpret_cast<const char*>(xl) + byte);
                }
#pragma unroll
                for (int mf = 0; mf < 2; ++mf) {
                    acc[mf][0] = __builtin_amdgcn_mfma_f32_16x16x32_bf16(afr[mf], wreg[ij][cs][0], acc[mf][0], 0, 0, 0);
                    acc[mf][1] = __builtin_amdgcn_mfma_f32_16x16x32_bf16(afr[mf], wreg[ij][cs][1], acc[mf][1], 0, 0, 0);
                }
            }
        }

        // ---- Epilogue: D layout col=lane&15 (o), row=(lane>>4)*4+reg (w) ----
        const int h = h0 + r;
#pragma unroll
        for (int nf = 0; nf < 2; ++nf) {
            int o = o0 + nf * 16 + lr;
            float bv = nf ? bv1 : bv0;
#pragma unroll
            for (int mf = 0; mf < 2; ++mf) {
                int w0 = m0 + mf * 16 + lg * 4;
                float* dst = y + (((size_t)b * 64 + o) * 128 + h) * 128 + w0;
                f32x4 out;
                out[0] = acc[mf][nf][0] + bv;
                out[1] = acc[mf][nf][1] + bv;
                out[2] = acc[mf][nf][2] + bv;
                out[3] = acc[mf][nf][3] + bv;
                *reinterpret_cast<f32x4*>(dst) = out;
            }
        }

        // Barrier every 2 rows (after rows 1,3,5). Hazard ledger: a slot
        // written at row r is first read at row r+2 and last-read-before-
        // overwrite at row r-2 -> one barrier inside each 2-row window in
        // both directions suffices (checked per slot for r=0..7).
        if ((r & 1) && r < 7) __syncthreads();
        slA = slB;
    }
}

extern "C" void kernel_launch(void* const* d_in, const int* in_sizes, int n_in,
                              void* d_out, int out_size, void* d_ws, size_t ws_size,
                              hipStream_t stream) {
    const float* x    = (const float*)d_in[0];
    const float* wt   = (const float*)d_in[1];
    const float* bias = (const float*)d_in[2];
    float* y = (float*)d_out;
    (void)d_ws; (void)ws_size;                // fused kernel needs no workspace

    hipLaunchKernelGGL(conv_main, dim3(B_N * H_N / 8), dim3(512), 0, stream,
                       x, wt, bias, y);
}